// Round 4
// baseline (31.055 us; speedup 1.0000x reference)
//
#include <hip/hip_runtime.h>
#include <math.h>

#define BB   4      // batch
#define HH   32     // query heads
#define GG   4      // query groups (also KV heads)
#define HPG  8      // heads per group
#define DD   128    // head dim
#define NCK  128    // number of compressed keys per head
#define SEQ  8192   // key/value sequence length
#define NSEL 16     // selected blocks
#define BLK  64     // block size

// One block per (bg, s): recompute the group's selection (bit-identical across
// the 16 blocks sharing a bg), then copy that s-th selected K and V block.
// Single launch, no workspace, no inter-block dependencies.
__global__ __launch_bounds__(1024, 1) void fused_selector_gather(
    const float* __restrict__ query,
    const float* __restrict__ ck,
    const float* __restrict__ keys,
    const float* __restrict__ values,
    float* __restrict__ out)
{
    const int bid  = blockIdx.x;               // 0..255
    // XCD-grouped mapping (XCD = bid&7 round-robin): the 16 blocks of one bg
    // share one XCD's L2 for their 512 KB ck slice.
    const int bg   = 2 * (bid & 7) + (bid >> 7);   // 0..15
    const int sown = (bid >> 3) & 15;              // rank this block copies
    const int b    = bg >> 2;
    const int g    = bg & 3;
    const int t    = threadIdx.x;              // 0..1023
    const int r    = t >> 3;                   // compressed-key row 0..127
    const int sub  = t & 7;                    // eighth of the row
    const int w    = t >> 6;                   // wave 0..15

    __shared__ float q_sh[HPG][DD];            // 4 KB
    __shared__ float red_m[16][HPG];           // per-wave per-head max
    __shared__ float red_s[16][HPG];           // per-wave per-head expsum (x8 dup)
    __shared__ float pm[NCK];                  // group-mean probs
    __shared__ int   sel_sh;

    // stage the 8 query rows
    {
        const int j = t >> 7, d = t & 127;
        q_sh[j][d] = query[(size_t)(b * HH + g * HPG + j) * DD + d];
    }
    __syncthreads();

    // scores: thread (r,sub) holds dot(q[j], ck[j][r]) for all 8 heads
    float sc[HPG];
    const size_t ck_row = ((size_t)(b * HH + g * HPG) * NCK + r) * DD;
    #pragma unroll
    for (int j = 0; j < HPG; ++j) {
        const float4* c4 = (const float4*)(ck + ck_row + (size_t)j * NCK * DD);
        const float4* q4 = (const float4*)&q_sh[j][0];
        float s = 0.0f;
        #pragma unroll
        for (int i = 0; i < 4; ++i) {
            float4 a = q4[i * 8 + sub];
            float4 c = c4[i * 8 + sub];   // 8 lanes -> one contiguous 128B line
            s += a.x * c.x + a.y * c.y + a.z * c.z + a.w * c.w;
        }
        s += __shfl_xor(s, 1);
        s += __shfl_xor(s, 2);
        s += __shfl_xor(s, 4);            // bit-identical on all 8 lanes
        sc[j] = s * 0.08838834764831845f; // 1/sqrt(128)
    }

    // per-head wave max (8 rows x8 dup per wave; dup harmless for max)
    #pragma unroll
    for (int j = 0; j < HPG; ++j) {
        float wm = sc[j];
        #pragma unroll
        for (int off = 1; off < 64; off <<= 1) wm = fmaxf(wm, __shfl_xor(wm, off));
        if ((t & 63) == 0) red_m[w][j] = wm;
    }
    __syncthreads();

    float e[HPG];
    #pragma unroll
    for (int j = 0; j < HPG; ++j) {
        float m = red_m[0][j];
        #pragma unroll
        for (int ww = 1; ww < 16; ++ww) m = fmaxf(m, red_m[ww][j]);
        e[j] = expf(sc[j] - m);
        float wsum = e[j];                // butterfly sum counts each row 8x
        #pragma unroll
        for (int off = 1; off < 64; off <<= 1) wsum += __shfl_xor(wsum, off);
        if ((t & 63) == 0) red_s[w][j] = wsum;
    }
    __syncthreads();

    float pmean = 0.0f;
    #pragma unroll
    for (int j = 0; j < HPG; ++j) {
        float S8 = red_s[0][j];
        #pragma unroll
        for (int ww = 1; ww < 16; ++ww) S8 += red_s[ww][j];
        pmean += 8.0f * e[j] / S8;        // = e/sum, dup factor folded
    }
    pmean *= 0.125f;                      // mean over 8 heads
    if (sub == 0) pm[r] = pmean;
    __syncthreads();

    // top-16 on wave 0: two rows per lane, lax.top_k tie semantics
    if (t < 64) {
        float v0 = pm[t], v1 = pm[t + 64];
        for (int k = 0; k < NSEL; ++k) {
            float rv; int ri;
            if (v0 >= v1) { rv = v0; ri = t; }      // tie -> lower index
            else          { rv = v1; ri = t + 64; }
            #pragma unroll
            for (int off = 1; off < 64; off <<= 1) {
                float ov = __shfl_xor(rv, off);
                int   oi = __shfl_xor(ri, off);
                if (ov > rv || (ov == rv && oi < ri)) { rv = ov; ri = oi; }
            }
            if (k == sown && t == 0) sel_sh = ri;
            if (ri == t)           v0 = -INFINITY;
            else if (ri == t + 64) v1 = -INFINITY;
        }
    }
    __syncthreads();
    const int sel = sel_sh;

    // copy the selected 64x128 K and V blocks (2048 float4 each)
    const size_t src  = ((size_t)bg * SEQ + (size_t)sel * BLK) * DD;
    const size_t dst  = ((size_t)bg * (NSEL * BLK) + (size_t)sown * BLK) * DD;
    const size_t VOFF = (size_t)BB * GG * NSEL * BLK * DD;

    const float4* ks = (const float4*)(keys + src);
    const float4* vs = (const float4*)(values + src);
    float4* kd = (float4*)(out + dst);
    float4* vd = (float4*)(out + VOFF + dst);

    kd[t]        = ks[t];
    kd[t + 1024] = ks[t + 1024];
    vd[t]        = vs[t];
    vd[t + 1024] = vs[t + 1024];
}

extern "C" void kernel_launch(void* const* d_in, const int* in_sizes, int n_in,
                              void* d_out, int out_size, void* d_ws, size_t ws_size,
                              hipStream_t stream) {
    const float* query  = (const float*)d_in[0];   // (4,32,1,128)
    const float* ck     = (const float*)d_in[1];   // (4,32,128,128)
    const float* keys   = (const float*)d_in[2];   // (4,4,8192,128)
    const float* values = (const float*)d_in[3];   // (4,4,8192,128)
    float* out = (float*)d_out;

    fused_selector_gather<<<BB * GG * NSEL, 1024, 0, stream>>>(query, ck, keys, values, out);
}

// Round 5
// 25.861 us; speedup vs baseline: 1.2009x; 1.2009x over previous
//
#include <hip/hip_runtime.h>
#include <math.h>

#define BB   4      // batch
#define HH   32     // query heads
#define GG   4      // query groups (also KV heads)
#define HPG  8      // heads per group
#define DD   128    // head dim
#define NCK  128    // number of compressed keys per head
#define SEQ  8192   // key/value sequence length
#define NSEL 16     // selected blocks
#define BLK  64     // block size

// Kernel 1: one block per (b,h). 512 threads = 4 threads per compressed-key row.
// Coalesced dot + wave-shuffle softmax. Writes per-head probs to ws. (R3, proven)
__global__ __launch_bounds__(512, 1) void scores_kernel(const float* __restrict__ query,
                                                        const float* __restrict__ ck,
                                                        float* __restrict__ probs_out) {
    const int bh  = blockIdx.x;          // 0..127  (b*HH + h)
    const int t   = threadIdx.x;         // 0..511
    const int r   = t >> 2;              // row 0..127
    const int sub = t & 3;               // quarter of the row
    const int w   = t >> 6;              // wave 0..7

    __shared__ float q_sh[DD];
    __shared__ float wred[8];

    if (t < DD) q_sh[t] = query[(size_t)bh * DD + t];
    __syncthreads();

    const float4* q4 = ((const float4*)q_sh) + sub * 8;
    const float4* c4 = (const float4*)(ck + ((size_t)bh * NCK + r) * DD + sub * 32);
    float s = 0.0f;
    #pragma unroll
    for (int i = 0; i < 8; ++i) {
        float4 a = q4[i], c = c4[i];
        s += a.x * c.x + a.y * c.y + a.z * c.z + a.w * c.w;
    }
    s += __shfl_xor(s, 1);
    s += __shfl_xor(s, 2);
    s *= 0.08838834764831845f;           // 1/sqrt(128)

    float wm = s;
    #pragma unroll
    for (int off = 1; off < 64; off <<= 1) wm = fmaxf(wm, __shfl_xor(wm, off));
    if ((t & 63) == 0) wred[w] = wm;
    __syncthreads();
    float m = wred[0];
    #pragma unroll
    for (int i = 1; i < 8; ++i) m = fmaxf(m, wred[i]);
    __syncthreads();

    const float e = expf(s - m);

    float ws_ = e;                        // butterfly counts each row 4x
    #pragma unroll
    for (int off = 1; off < 64; off <<= 1) ws_ += __shfl_xor(ws_, off);
    if ((t & 63) == 0) wred[w] = ws_;
    __syncthreads();
    float S4 = wred[0];
    #pragma unroll
    for (int i = 1; i < 8; ++i) S4 += wred[i];

    if (sub == 0) probs_out[(size_t)bh * NCK + r] = 4.0f * e / S4;
}

// Kernel 2: one block per (bg, s). Re-derive rank-s index from probs (identical
// arithmetic to the proven topk), then copy that K and V block. 512 threads.
__global__ __launch_bounds__(512, 1) void topk_gather_kernel(const float* __restrict__ probs,
                                                             const float* __restrict__ keys,
                                                             const float* __restrict__ values,
                                                             float* __restrict__ out) {
    const int bid  = blockIdx.x;         // 0..255
    const int bg   = bid >> 4;           // 0..15
    const int sown = bid & 15;           // which rank this block copies
    const int b    = bg >> 2;
    const int g    = bg & 3;
    const int t    = threadIdx.x;        // 0..511

    __shared__ float cand_v[2];
    __shared__ int   cand_i[2];
    __shared__ int   winner;
    __shared__ int   sel_sh;

    float myv = -INFINITY;
    if (t < NCK) {
        myv = 0.0f;
        #pragma unroll
        for (int jj = 0; jj < HPG; ++jj)
            myv += probs[(size_t)(b * HH + g * HPG + jj) * NCK + t];
        myv *= 0.125f;
    }

    for (int k = 0; k <= sown; ++k) {
        if (t < NCK) {
            float rv = myv;
            int   ri = t;
            #pragma unroll
            for (int off = 1; off < 64; off <<= 1) {
                float ov = __shfl_xor(rv, off);
                int   oi = __shfl_xor(ri, off);
                if (ov > rv || (ov == rv && oi < ri)) { rv = ov; ri = oi; }
            }
            if ((t & 63) == 0) { cand_v[t >> 6] = rv; cand_i[t >> 6] = ri; }
        }
        __syncthreads();
        if (t == 0) {
            // wave1 indices all exceed wave0's, so strict > keeps lower-index ties
            const int wi = (cand_v[1] > cand_v[0]) ? cand_i[1] : cand_i[0];
            winner = wi;
            if (k == sown) sel_sh = wi;
        }
        __syncthreads();
        if (t == winner) myv = -INFINITY;
    }

    const int sel = sel_sh;

    const size_t src  = ((size_t)bg * SEQ + (size_t)sel * BLK) * DD;
    const size_t dst  = ((size_t)bg * (NSEL * BLK) + (size_t)sown * BLK) * DD;
    const size_t VOFF = (size_t)BB * GG * NSEL * BLK * DD;

    const float4* ks = (const float4*)(keys + src);
    const float4* vs = (const float4*)(values + src);
    float4* kd = (float4*)(out + dst);
    float4* vd = (float4*)(out + VOFF + dst);

    #pragma unroll
    for (int i = 0; i < 4; ++i) kd[i * 512 + t] = ks[i * 512 + t];
    #pragma unroll
    for (int i = 0; i < 4; ++i) vd[i * 512 + t] = vs[i * 512 + t];
}

extern "C" void kernel_launch(void* const* d_in, const int* in_sizes, int n_in,
                              void* d_out, int out_size, void* d_ws, size_t ws_size,
                              hipStream_t stream) {
    const float* query  = (const float*)d_in[0];   // (4,32,1,128)
    const float* ck     = (const float*)d_in[1];   // (4,32,128,128)
    const float* keys   = (const float*)d_in[2];   // (4,4,8192,128)
    const float* values = (const float*)d_in[3];   // (4,4,8192,128)
    float* out = (float*)d_out;

    float* probs = (float*)d_ws;                   // 4*32*128 floats = 64 KB

    scores_kernel<<<BB * HH, 512, 0, stream>>>(query, ck, probs);
    topk_gather_kernel<<<BB * GG * NSEL, 512, 0, stream>>>(probs, keys, values, out);
}

// Round 6
// 22.149 us; speedup vs baseline: 1.4021x; 1.1676x over previous
//
#include <hip/hip_runtime.h>
#include <math.h>

#define BB   4      // batch
#define HH   32     // query heads
#define GG   4      // query groups (also KV heads)
#define HPG  8      // heads per group
#define DD   128    // head dim
#define NCK  128    // number of compressed keys per head
#define SEQ  8192   // key/value sequence length
#define NSEL 16     // selected blocks
#define BLK  64     // block size

// Kernel 1: pure GEMV. One block per (b,h,half): 64 rows x 8 lanes/row.
// Writes raw scaled scores to ws. One barrier, no softmax -> releases fast.
__global__ __launch_bounds__(512, 1) void gemv_kernel(const float* __restrict__ query,
                                                      const float* __restrict__ ck,
                                                      float* __restrict__ scores_out) {
    const int blk  = blockIdx.x;         // 0..255
    const int bh   = blk >> 1;           // 0..127
    const int half = blk & 1;
    const int t    = threadIdx.x;        // 0..511
    const int r    = (t >> 3) + half * 64;   // row 0..127
    const int sub  = t & 7;

    __shared__ float q_sh[DD];
    if (t < DD) q_sh[t] = query[(size_t)bh * DD + t];
    __syncthreads();

    const float4* c4 = (const float4*)(ck + ((size_t)bh * NCK + r) * DD) + sub;
    const float4* q4 = ((const float4*)q_sh) + sub;
    float s = 0.0f;
    #pragma unroll
    for (int i = 0; i < 4; ++i) {
        float4 a = q4[i * 8];
        float4 c = c4[i * 8];
        s += a.x * c.x + a.y * c.y + a.z * c.z + a.w * c.w;
    }
    s += __shfl_xor(s, 1);
    s += __shfl_xor(s, 2);
    s += __shfl_xor(s, 4);               // all 8 lanes of the row identical

    if (sub == 0) scores_out[(size_t)bh * NCK + r] = s * 0.08838834764831845f;
}

// Kernel 2: one block per (bg, s). Softmax over raw scores (4 KB), group mean,
// rank-based selection (no serial top-k loop), then copy the K and V block.
__global__ __launch_bounds__(512, 1) void select_gather_kernel(const float* __restrict__ scores,
                                                               const float* __restrict__ keys,
                                                               const float* __restrict__ values,
                                                               float* __restrict__ out) {
    const int bid  = blockIdx.x;         // 0..255
    const int bg   = bid >> 4;           // 0..15
    const int sown = bid & 15;           // rank this block copies
    const int b    = bg >> 2;
    const int g    = bg & 3;
    const int t    = threadIdx.x;        // 0..511
    const int w    = t >> 6;             // wave id (0..7; selection uses 0,1)

    __shared__ float redm[2][HPG];
    __shared__ float reds[2][HPG];
    __shared__ float pm[NCK];
    __shared__ int   sel_sh;

    float sc[HPG];
    float e[HPG];

    // wave0 holds rows 0..63, wave1 rows 64..127
    if (t < NCK) {
        #pragma unroll
        for (int j = 0; j < HPG; ++j)
            sc[j] = scores[(size_t)(b * HH + g * HPG + j) * NCK + t];
        #pragma unroll
        for (int j = 0; j < HPG; ++j) {
            float m = sc[j];
            #pragma unroll
            for (int off = 1; off < 64; off <<= 1) m = fmaxf(m, __shfl_xor(m, off));
            if ((t & 63) == 0) redm[w][j] = m;
        }
    }
    __syncthreads();

    if (t < NCK) {
        #pragma unroll
        for (int j = 0; j < HPG; ++j) {
            const float m = fmaxf(redm[0][j], redm[1][j]);
            e[j] = expf(sc[j] - m);
            float ssum = e[j];
            #pragma unroll
            for (int off = 1; off < 64; off <<= 1) ssum += __shfl_xor(ssum, off);
            if ((t & 63) == 0) reds[w][j] = ssum;
        }
    }
    __syncthreads();

    if (t < NCK) {
        float p = 0.0f;
        #pragma unroll
        for (int j = 0; j < HPG; ++j) p += e[j] / (reds[0][j] + reds[1][j]);
        pm[t] = p * 0.125f;
    }
    __syncthreads();

    // rank of row t among the 128 (stable descending = lax.top_k order)
    if (t < NCK) {
        const float mv = pm[t];
        int rank = 0;
        for (int i = 0; i < NCK; ++i) {
            const float vi = pm[i];           // uniform index -> LDS broadcast
            if (vi > mv || (vi == mv && i < t)) ++rank;
        }
        if (rank == sown) sel_sh = t;         // exactly one thread matches
    }
    __syncthreads();
    const int sel = sel_sh;

    // copy the selected 64x128 K and V blocks (2048 float4 each, 512 threads)
    const size_t src  = ((size_t)bg * SEQ + (size_t)sel * BLK) * DD;
    const size_t dst  = ((size_t)bg * (NSEL * BLK) + (size_t)sown * BLK) * DD;
    const size_t VOFF = (size_t)BB * GG * NSEL * BLK * DD;

    const float4* ks = (const float4*)(keys + src);
    const float4* vs = (const float4*)(values + src);
    float4* kd = (float4*)(out + dst);
    float4* vd = (float4*)(out + VOFF + dst);

    #pragma unroll
    for (int i = 0; i < 4; ++i) kd[i * 512 + t] = ks[i * 512 + t];
    #pragma unroll
    for (int i = 0; i < 4; ++i) vd[i * 512 + t] = vs[i * 512 + t];
}

extern "C" void kernel_launch(void* const* d_in, const int* in_sizes, int n_in,
                              void* d_out, int out_size, void* d_ws, size_t ws_size,
                              hipStream_t stream) {
    const float* query  = (const float*)d_in[0];   // (4,32,1,128)
    const float* ck     = (const float*)d_in[1];   // (4,32,128,128)
    const float* keys   = (const float*)d_in[2];   // (4,4,8192,128)
    const float* values = (const float*)d_in[3];   // (4,4,8192,128)
    float* out = (float*)d_out;

    float* scores = (float*)d_ws;                  // 4*32*128 floats = 64 KB

    gemv_kernel<<<BB * HH * 2, 512, 0, stream>>>(query, ck, scores);
    select_gather_kernel<<<BB * GG * NSEL, 512, 0, stream>>>(scores, keys, values, out);
}